// Round 1
// baseline (814.375 us; speedup 1.0000x reference)
//
#include <hip/hip_runtime.h>
#include <hip/hip_bf16.h>
#include <cstdint>

// Problem constants (setup_inputs: B=8, H=W=512, num_erosions=2)
static constexpr int B = 8;
static constexpr int H = 512;
static constexpr int W = 512;
static constexpr int HW = H * W;
static constexpr int NPIX = B * HW;

// ---------------- endpoint kernel masks (compile-time constants) -------------
template <int N> struct Mask { bool b[N]; };
template <int N> constexpr Mask<N> mk(const char* s) {
    Mask<N> m{};
    for (int i = 0; i < N; i++) m.b[i] = (s[i] == '1');
    return m;
}
constexpr Mask<9> K3[8] = {
    mk<9>("111001111"), mk<9>("111101101"), mk<9>("111100111"), mk<9>("101101111"),
    mk<9>("011101111"), mk<9>("111101011"), mk<9>("111101110"), mk<9>("110101111")};
constexpr Mask<16> K4[8] = {
    mk<16>("0011000110011111"), mk<16>("1100100010011111"),
    mk<16>("1111100100010011"), mk<16>("1111100110001100"),
    mk<16>("1001100110011111"), mk<16>("1111000100011111"),
    mk<16>("1111100110011001"), mk<16>("1111100010001111")};
constexpr Mask<25> K5[8] = {
    mk<25>("0001100001000011000111111"), mk<25>("1100010000100001000111111"),
    mk<25>("1111110001100001000011000"), mk<25>("1111110001000010000100011"),
    mk<25>("1111110000100001000011111"), mk<25>("1111100001000010000111111"),
    mk<25>("1111110001100011000110001"), mk<25>("1000110001100011000111111")};
constexpr Mask<36> K6[7] = {  // reference uses only the first 7 of the 8 K6 masks
    mk<36>("000011000001000001000001100001111111"),
    mk<36>("110000100000100000100000100001111111"),
    mk<36>("111111100001100000100000100000110000"),
    mk<36>("111111100001000001000001000001000011"),
    mk<36>("111111100000100000100000100000111111"),
    mk<36>("111111000001000001000001000001111111"),
    mk<36>("111111100001100001100001100001100001")};

// ---------------- helpers ----------------------------------------------------
__device__ __forceinline__ float sigm(float z) {
    // sigmoid(z) = 1/(1+exp(-z)); rcp approx is ~1ulp, fine vs 2% scalar tol
    return __builtin_amdgcn_rcpf(1.0f + __expf(-z));
}
__device__ __forceinline__ float endsig(float nc) {
    float z = fminf(fmaxf(-10.0f * (nc - 1.0f), -10.0f), 10.0f);
    return sigm(z);
}
__device__ __forceinline__ void atomicMaxPos(float* a, float v) {
    // valid for non-negative floats (bit pattern order == float order)
    atomicMax((int*)a, __float_as_int(v));
}

// ---------------- global max of a non-negative tensor ------------------------
__global__ __launch_bounds__(256) void gmax_kernel(const float* __restrict__ x,
                                                   float* slot) {
    float m = 0.0f;
    for (int idx = blockIdx.x * 256 + threadIdx.x; idx < NPIX;
         idx += gridDim.x * 256)
        m = fmaxf(m, x[idx]);
#pragma unroll
    for (int o = 32; o > 0; o >>= 1) m = fmaxf(m, __shfl_down(m, o, 64));
    __shared__ float red[4];
    int tid = threadIdx.x;
    if ((tid & 63) == 0) red[tid >> 6] = m;
    __syncthreads();
    if (tid == 0)
        atomicMaxPos(slot, fmaxf(fmaxf(red[0], red[1]), fmaxf(red[2], red[3])));
}

// ---------------- erosion stage 1: cross conv + global max of t --------------
__global__ __launch_bounds__(256) void cross_max_kernel(const float* __restrict__ x,
                                                        float* __restrict__ t,
                                                        float* slot) {
    float m = 0.0f;
    for (int idx = blockIdx.x * 256 + threadIdx.x; idx < NPIX;
         idx += gridDim.x * 256) {
        int i = idx & (HW - 1);
        int y = i >> 9;
        int c = i & (W - 1);
        float v = 0.0f;
        if (y > 0)     v += x[idx - W];
        if (y < H - 1) v += x[idx + W];
        if (c > 0)     v += x[idx - 1];
        if (c < W - 1) v += x[idx + 1];
        t[idx] = v;
        m = fmaxf(m, v);
    }
#pragma unroll
    for (int o = 32; o > 0; o >>= 1) m = fmaxf(m, __shfl_down(m, o, 64));
    __shared__ float red[4];
    int tid = threadIdx.x;
    if ((tid & 63) == 0) red[tid >> 6] = m;
    __syncthreads();
    if (tid == 0)
        atomicMaxPos(slot, fmaxf(fmaxf(red[0], red[1]), fmaxf(red[2], red[3])));
}

// ---------------- erosion stage 2: y = sig2(t/(tmax+1e-8), 0.7, 10) ----------
// Also writes max(y) in closed form (sigmoid monotone in t => max y = f(tmax)).
__global__ __launch_bounds__(256) void erode_norm_kernel(const float* __restrict__ t,
                                                         const float* tmaxSlot,
                                                         float* __restrict__ y,
                                                         float* ymaxSlot) {
    float tmax = *tmaxSlot;
    float inv = 1.0f / (tmax + 1e-8f);
    for (int idx = blockIdx.x * 256 + threadIdx.x; idx < NPIX;
         idx += gridDim.x * 256)
        y[idx] = sigm(10.0f * (t[idx] * inv - 0.7f));
    if (blockIdx.x == 0 && threadIdx.x == 0)
        *ymaxSlot = sigm(10.0f * (tmax * inv - 0.7f));
}

// ---------------- cp_map: 31 masked convs + sigmoids + final sigmoid ---------
// value at padded coord (pr,pc): OOB(<0 or >513)->0, border(0 or 513)->1,
// interior -> base + sign*x  (base=0,sign=+1 direct; base=M,sign=-1 complement)
__global__ __launch_bounds__(256) void cp_map_kernel(const float* __restrict__ x,
                                                     const float* baseSlot,
                                                     float sign,
                                                     float* __restrict__ out) {
    __shared__ float sm[21][22];
    const int b = blockIdx.z;
    const int oy0 = blockIdx.y * 16;
    const int ox0 = blockIdx.x * 16;
    const float base = *baseSlot;
    const float* xb = x + b * HW;
    const int tid = threadIdx.y * 16 + threadIdx.x;
    // padded rows oy0-2 .. oy0+18 (21), cols likewise
    for (int i2 = tid; i2 < 21 * 21; i2 += 256) {
        int r = i2 / 21, c = i2 % 21;
        int pr = oy0 - 2 + r;
        int pc = ox0 - 2 + c;
        float v;
        if (pr < 0 || pr > H + 1 || pc < 0 || pc > W + 1) v = 0.0f;
        else if (pr == 0 || pr == H + 1 || pc == 0 || pc == W + 1) v = 1.0f;
        else v = fmaf(sign, xb[(pr - 1) * W + (pc - 1)], base);
        sm[r][c] = v;
    }
    __syncthreads();

    // 6x6 register window: padded rows (py-3..py+2), py = oy0+1+ty
    float wnd[6][6];
#pragma unroll
    for (int r = 0; r < 6; r++)
#pragma unroll
        for (int c = 0; c < 6; c++)
            wnd[r][c] = sm[threadIdx.y + r][threadIdx.x + c];

    float ssum = 0.0f;
#pragma unroll
    for (int kk = 0; kk < 8; kk++) {  // k=3, pad=1 -> wnd rows 2..4
        float nc = 0.0f;
#pragma unroll
        for (int d = 0; d < 9; d++)
            if (K3[kk].b[d]) nc += wnd[2 + d / 3][2 + d % 3];
        ssum += endsig(nc);
    }
#pragma unroll
    for (int kk = 0; kk < 8; kk++) {  // k=4, pad=2 -> rows 1..4
        float nc = 0.0f;
#pragma unroll
        for (int d = 0; d < 16; d++)
            if (K4[kk].b[d]) nc += wnd[1 + d / 4][1 + d % 4];
        ssum += endsig(nc);
    }
#pragma unroll
    for (int kk = 0; kk < 8; kk++) {  // k=5, pad=2 -> rows 1..5
        float nc = 0.0f;
#pragma unroll
        for (int d = 0; d < 25; d++)
            if (K5[kk].b[d]) nc += wnd[1 + d / 5][1 + d % 5];
        ssum += endsig(nc);
    }
#pragma unroll
    for (int kk = 0; kk < 7; kk++) {  // k=6, pad=3 -> rows 0..5
        float nc = 0.0f;
#pragma unroll
        for (int d = 0; d < 36; d++)
            if (K6[kk].b[d]) nc += wnd[d / 6][d % 6];
        ssum += endsig(nc);
    }
    float v = wnd[3][3];                    // center (interior) value
    float cp = sigm(10.0f * (v * ssum - 0.5f));
    out[b * HW + (oy0 + threadIdx.y) * W + (ox0 + threadIdx.x)] = cp;
}

// ---------------- dilate(3x3 sum, clip<=1) of both maps, squared diff, reduce
__global__ __launch_bounds__(256) void dil_diff_kernel(const float* __restrict__ cpP,
                                                       const float* __restrict__ cpG,
                                                       float* acc) {
    float s = 0.0f;
    for (int idx = blockIdx.x * 256 + threadIdx.x; idx < NPIX;
         idx += gridDim.x * 256) {
        int i = idx & (HW - 1);
        int y = i >> 9;
        int c = i & (W - 1);
        int bb = idx - i;
        float sp = 0.0f, sg = 0.0f;
#pragma unroll
        for (int dy = -1; dy <= 1; dy++) {
            int yy = y + dy;
            if ((unsigned)yy < (unsigned)H) {
                int rb = bb + yy * W;
#pragma unroll
                for (int dx = -1; dx <= 1; dx++) {
                    int xx = c + dx;
                    if ((unsigned)xx < (unsigned)W) {
                        sp += cpP[rb + xx];
                        sg += cpG[rb + xx];
                    }
                }
            }
        }
        float d = fminf(sp, 1.0f) - fminf(sg, 1.0f);
        s += d * d;
    }
#pragma unroll
    for (int o = 32; o > 0; o >>= 1) s += __shfl_down(s, o, 64);
    __shared__ float red[4];
    int tid = threadIdx.x;
    if ((tid & 63) == 0) red[tid >> 6] = s;
    __syncthreads();
    if (tid == 0) atomicAdd(acc, red[0] + red[1] + red[2] + red[3]);
}

__global__ void finalize_kernel(const float* acc, float* out) {
    out[0] = acc[0] * (1.0f / (float)B);
}

// ---------------- launch -----------------------------------------------------
extern "C" void kernel_launch(void* const* d_in, const int* in_sizes, int n_in,
                              void* d_out, int out_size, void* d_ws, size_t ws_size,
                              hipStream_t stream) {
    (void)in_sizes; (void)n_in; (void)out_size; (void)ws_size;
    const float* pred = (const float*)d_in[0];
    const float* gt   = (const float*)d_in[1];
    float* out = (float*)d_out;

    // workspace layout (floats): slots[1024], P[N], G[N], CA[N], CB[N]
    // slots: 0..2 maxP chain, 3..5 maxG chain, 6 = zero const, 7 = loss acc,
    //        8..11 = t-max scratch per erosion.  Total ws = 4*(1024+4N) ~ 33.6MB
    float* S  = (float*)d_ws;
    float* P  = S + 1024;
    float* G  = P + NPIX;
    float* CA = G + NPIX;   // doubles as erosion t-buffer
    float* CB = CA + NPIX;

    hipMemsetAsync(S, 0, 64 * sizeof(float), stream);

    const dim3 b1(256), g1(1024);
    const dim3 b2(16, 16, 1), g2(W / 16, H / 16, B);

    auto level = [&](const float* p, const float* g, const float* mp,
                     const float* mg) {
        cp_map_kernel<<<g2, b2, 0, stream>>>(p, S + 6, 1.0f, CA);
        cp_map_kernel<<<g2, b2, 0, stream>>>(g, S + 6, 1.0f, CB);
        dil_diff_kernel<<<g1, b1, 0, stream>>>(CA, CB, S + 7);
        cp_map_kernel<<<g2, b2, 0, stream>>>(p, mp, -1.0f, CA);
        cp_map_kernel<<<g2, b2, 0, stream>>>(g, mg, -1.0f, CB);
        dil_diff_kernel<<<g1, b1, 0, stream>>>(CA, CB, S + 7);
    };

    // global maxes of raw inputs (for level-0 complement)
    gmax_kernel<<<g1, b1, 0, stream>>>(pred, S + 0);
    gmax_kernel<<<g1, b1, 0, stream>>>(gt, S + 3);

    // level 0 directly from inputs
    level(pred, gt, S + 0, S + 3);

    // erosion 1
    cross_max_kernel<<<g1, b1, 0, stream>>>(pred, CA, S + 8);
    erode_norm_kernel<<<g1, b1, 0, stream>>>(CA, S + 8, P, S + 1);
    cross_max_kernel<<<g1, b1, 0, stream>>>(gt, CA, S + 9);
    erode_norm_kernel<<<g1, b1, 0, stream>>>(CA, S + 9, G, S + 4);
    level(P, G, S + 1, S + 4);

    // erosion 2 (in place: t in CA, overwrite P/G)
    cross_max_kernel<<<g1, b1, 0, stream>>>(P, CA, S + 10);
    erode_norm_kernel<<<g1, b1, 0, stream>>>(CA, S + 10, P, S + 2);
    cross_max_kernel<<<g1, b1, 0, stream>>>(G, CA, S + 11);
    erode_norm_kernel<<<g1, b1, 0, stream>>>(CA, S + 11, G, S + 5);
    level(P, G, S + 2, S + 5);

    finalize_kernel<<<1, 1, 0, stream>>>(S + 7, out);
}

// Round 2
// 578.049 us; speedup vs baseline: 1.4088x; 1.4088x over previous
//
#include <hip/hip_runtime.h>
#include <cstdint>

// Problem constants (setup_inputs: B=8, H=W=512, num_erosions=2)
static constexpr int B = 8;
static constexpr int H = 512;
static constexpr int W = 512;
static constexpr int HW = H * W;
static constexpr int NPIX = B * HW;

// ---------------- endpoint kernel masks (compile-time constants) -------------
template <int N> struct Mask { bool b[N]; };
template <int N> constexpr Mask<N> mk(const char* s) {
    Mask<N> m{};
    for (int i = 0; i < N; i++) m.b[i] = (s[i] == '1');
    return m;
}
// K3 group handled via complement trick (all masks = S33 - center - one cell)
constexpr int KZ3[8] = {3, 7, 5, 1, 0, 6, 8, 2};  // the distinct missing cell
constexpr Mask<16> K4[8] = {
    mk<16>("0011000110011111"), mk<16>("1100100010011111"),
    mk<16>("1111100100010011"), mk<16>("1111100110001100"),
    mk<16>("1001100110011111"), mk<16>("1111000100011111"),
    mk<16>("1111100110011001"), mk<16>("1111100010001111")};
constexpr Mask<25> K5[8] = {
    mk<25>("0001100001000011000111111"), mk<25>("1100010000100001000111111"),
    mk<25>("1111110001100001000011000"), mk<25>("1111110001000010000100011"),
    mk<25>("1111110000100001000011111"), mk<25>("1111100001000010000111111"),
    mk<25>("1111110001100011000110001"), mk<25>("1000110001100011000111111")};
constexpr Mask<36> K6[7] = {  // reference uses only the first 7 of the 8 K6 masks
    mk<36>("000011000001000001000001100001111111"),
    mk<36>("110000100000100000100000100001111111"),
    mk<36>("111111100001100000100000100000110000"),
    mk<36>("111111100001000001000001000001000011"),
    mk<36>("111111100000100000100000100000111111"),
    mk<36>("111111000001000001000001000001111111"),
    mk<36>("111111100001100001100001100001100001")};
// ones-count index per mask into cM[] = {7M, 9M, 10M, 11M, 13M, 16M}
constexpr int CI4[8] = {1, 1, 1, 1, 2, 2, 2, 2};
constexpr int CI5[8] = {3, 3, 3, 3, 4, 4, 4, 4};
constexpr int CI6[7] = {4, 4, 4, 4, 5, 5, 5};

// ---------------- helpers ----------------------------------------------------
__device__ __forceinline__ float rcpf(float x) { return __builtin_amdgcn_rcpf(x); }
// sigmoid(clip(-10(nc-1),-10,10)) with clip dropped (err <= 4.55e-5 per term)
__device__ __forceinline__ float endsig(float nc) {
    return rcpf(1.0f + __expf(fmaf(nc, 10.0f, -10.0f)));
}
// sigmoid(10(x-0.5))
__device__ __forceinline__ float sig_cp(float x) {
    return rcpf(1.0f + __expf(fmaf(x, -10.0f, 5.0f)));
}
// sigmoid(10(r-0.7))
__device__ __forceinline__ float sig_er(float r) {
    return rcpf(1.0f + __expf(fmaf(r, -10.0f, 7.0f)));
}
__device__ __forceinline__ void atomicMaxPos(float* a, float v) {
    atomicMax((int*)a, __float_as_int(v));  // valid for non-negative floats
}
__device__ __forceinline__ float wave_max(float m) {
#pragma unroll
    for (int o = 32; o > 0; o >>= 1) m = fmaxf(m, __shfl_down(m, o, 64));
    return m;
}
__device__ __forceinline__ float wave_sum(float s) {
#pragma unroll
    for (int o = 32; o > 0; o >>= 1) s += __shfl_down(s, o, 64);
    return s;
}

// ---------------- mask conv sums + sigmoids over one 6x6 window --------------
// PAIR=true: also accumulate complement ssum via nc_comp = cnt*M - nc_dir
// (valid only when every tap of the window is an interior pixel).
template <bool PAIR>
__device__ __forceinline__ void mask_ssums(const float (&w)[6][6], const float* cM,
                                           float& sD, float& sC) {
    float s = 0.0f, sc = 0.0f;
    // K3: all 8 masks = S33 - center - one distinct cell
    float S33 = w[2][2] + w[2][3] + w[2][4] + w[3][2] + w[3][3] + w[3][4] +
                w[4][2] + w[4][3] + w[4][4];
    float T = S33 - w[3][3];
#pragma unroll
    for (int k = 0; k < 8; k++) {
        float nc = T - w[2 + KZ3[k] / 3][2 + KZ3[k] % 3];
        s += endsig(nc);
        if constexpr (PAIR) sc += endsig(cM[0] - nc);
    }
#pragma unroll
    for (int k = 0; k < 8; k++) {  // k=4, pad=2 -> rows/cols 1..4
        float nc = 0.0f;
#pragma unroll
        for (int d = 0; d < 16; d++)
            if (K4[k].b[d]) nc += w[1 + d / 4][1 + d % 4];
        s += endsig(nc);
        if constexpr (PAIR) sc += endsig(cM[CI4[k]] - nc);
    }
#pragma unroll
    for (int k = 0; k < 8; k++) {  // k=5, pad=2 -> rows/cols 1..5
        float nc = 0.0f;
#pragma unroll
        for (int d = 0; d < 25; d++)
            if (K5[k].b[d]) nc += w[1 + d / 5][1 + d % 5];
        s += endsig(nc);
        if constexpr (PAIR) sc += endsig(cM[CI5[k]] - nc);
    }
#pragma unroll
    for (int k = 0; k < 7; k++) {  // k=6, pad=3 -> rows/cols 0..5
        float nc = 0.0f;
#pragma unroll
        for (int d = 0; d < 36; d++)
            if (K6[k].b[d]) nc += w[d / 6][d % 6];
        s += endsig(nc);
        if constexpr (PAIR) sc += endsig(cM[CI6[k]] - nc);
    }
    sD = s;
    sC = sc;
}

// ---------------- cp_quad: 4 cp maps (P/G x direct/complement) per pixel -----
// LDS stride 48 floats: row parity gives disjoint 16-bank halves -> only
// 2-way conflicts (free) on the 6x6 window reads.
__global__ __launch_bounds__(256) void cp_quad_kernel(
    const float* __restrict__ xP, const float* __restrict__ xG,
    const float* __restrict__ MPslot, const float* __restrict__ MGslot,
    float* __restrict__ cp) {
    __shared__ float sm[4][21][48];
    const int b = blockIdx.z;
    const int oy0 = blockIdx.y * 16;
    const int ox0 = blockIdx.x * 16;
    const float MP = *MPslot, MG = *MGslot;
    const bool edge = (blockIdx.x == 0) | (blockIdx.x == (W / 16 - 1)) |
                      (blockIdx.y == 0) | (blockIdx.y == (H / 16 - 1));
    const float* pb = xP + b * HW;
    const float* gb = xG + b * HW;
    const int tid = threadIdx.y * 16 + threadIdx.x;

    if (!edge) {
        // whole 21x21 halo is interior: padded (pr,pc) -> actual (pr-1,pc-1)
        for (int i = tid; i < 21 * 21; i += 256) {
            int r = i / 21, c = i % 21;
            int a = (oy0 - 3 + r) * W + (ox0 - 3 + c);
            sm[0][r][c] = pb[a];
            sm[1][r][c] = gb[a];
        }
    } else {
        for (int i = tid; i < 21 * 21; i += 256) {
            int r = i / 21, c = i % 21;
            int pr = oy0 - 2 + r;
            int pc = ox0 - 2 + c;
            float pd, gd, pc_, gc_;
            if (pr < 0 || pr > H + 1 || pc < 0 || pc > W + 1) {
                pd = gd = pc_ = gc_ = 0.0f;                       // conv zero-pad
            } else if (pr == 0 || pr == H + 1 || pc == 0 || pc == W + 1) {
                pd = gd = pc_ = gc_ = 1.0f;                       // image 1-pad
            } else {
                float xv = pb[(pr - 1) * W + (pc - 1)];
                float gv = gb[(pr - 1) * W + (pc - 1)];
                pd = xv;  gd = gv;
                pc_ = MP - xv;  gc_ = MG - gv;
            }
            sm[0][r][c] = pd;  sm[1][r][c] = gd;
            sm[2][r][c] = pc_; sm[3][r][c] = gc_;
        }
    }
    __syncthreads();

    const int ty = threadIdx.y, tx = threadIdx.x;
    float wnd[6][6];
    auto loadw = [&](int t) {
#pragma unroll
        for (int r = 0; r < 6; r++)
#pragma unroll
            for (int c = 0; c < 6; c++) wnd[r][c] = sm[t][ty + r][tx + c];
    };

    float sPd, sPc, sGd, sGc, vPd, vPc, vGd, vGc, junk;
    if (!edge) {
        const float cMP[6] = {7 * MP, 9 * MP, 10 * MP, 11 * MP, 13 * MP, 16 * MP};
        const float cMG[6] = {7 * MG, 9 * MG, 10 * MG, 11 * MG, 13 * MG, 16 * MG};
        loadw(0);
        mask_ssums<true>(wnd, cMP, sPd, sPc);
        vPd = wnd[3][3];  vPc = MP - vPd;
        loadw(1);
        mask_ssums<true>(wnd, cMG, sGd, sGc);
        vGd = wnd[3][3];  vGc = MG - vGd;
    } else {
        loadw(0); mask_ssums<false>(wnd, nullptr, sPd, junk); vPd = wnd[3][3];
        loadw(2); mask_ssums<false>(wnd, nullptr, sPc, junk); vPc = wnd[3][3];
        loadw(1); mask_ssums<false>(wnd, nullptr, sGd, junk); vGd = wnd[3][3];
        loadw(3); mask_ssums<false>(wnd, nullptr, sGc, junk); vGc = wnd[3][3];
    }
    const int o = b * HW + (oy0 + ty) * W + (ox0 + tx);
    cp[0 * NPIX + o] = sig_cp(vPd * sPd);
    cp[1 * NPIX + o] = sig_cp(vGd * sGd);
    cp[2 * NPIX + o] = sig_cp(vPc * sPc);
    cp[3 * NPIX + o] = sig_cp(vGc * sGc);
}

// ---------------- erosion: cross-conv max pass (no t store) ------------------
// Also tracks raw max of the inputs (needed as complement base for this level).
__global__ __launch_bounds__(256) void cross_max_both_kernel(
    const float* __restrict__ xP, const float* __restrict__ xG,
    float* tmaxP, float* tmaxG, float* rmaxP, float* rmaxG) {
    float mtP = 0.0f, mtG = 0.0f, mrP = 0.0f, mrG = 0.0f;
    for (int idx = blockIdx.x * 256 + threadIdx.x; idx < NPIX;
         idx += gridDim.x * 256) {
        int i = idx & (HW - 1);
        int y = i >> 9;
        int c = i & (W - 1);
        float tP = 0.0f, tG = 0.0f;
        if (y > 0)     { tP += xP[idx - W]; tG += xG[idx - W]; }
        if (y < H - 1) { tP += xP[idx + W]; tG += xG[idx + W]; }
        if (c > 0)     { tP += xP[idx - 1]; tG += xG[idx - 1]; }
        if (c < W - 1) { tP += xP[idx + 1]; tG += xG[idx + 1]; }
        mtP = fmaxf(mtP, tP);
        mtG = fmaxf(mtG, tG);
        mrP = fmaxf(mrP, xP[idx]);
        mrG = fmaxf(mrG, xG[idx]);
    }
    mtP = wave_max(mtP); mtG = wave_max(mtG);
    mrP = wave_max(mrP); mrG = wave_max(mrG);
    __shared__ float red[4][4];
    int tid = threadIdx.x;
    if ((tid & 63) == 0) {
        int w = tid >> 6;
        red[w][0] = mtP; red[w][1] = mtG; red[w][2] = mrP; red[w][3] = mrG;
    }
    __syncthreads();
    if (tid == 0) {
        atomicMaxPos(tmaxP, fmaxf(fmaxf(red[0][0], red[1][0]), fmaxf(red[2][0], red[3][0])));
        atomicMaxPos(tmaxG, fmaxf(fmaxf(red[0][1], red[1][1]), fmaxf(red[2][1], red[3][1])));
        atomicMaxPos(rmaxP, fmaxf(fmaxf(red[0][2], red[1][2]), fmaxf(red[2][2], red[3][2])));
        atomicMaxPos(rmaxG, fmaxf(fmaxf(red[0][3], red[1][3]), fmaxf(red[2][3], red[3][3])));
    }
}

// ---------------- erosion: recompute cross conv, normalize, sigmoid ----------
// y = sigmoid(10*(t/(tmax+1e-8) - 0.7)); also writes max(y) in closed form
// (sigmoid monotone in t => max y = f(tmax)).
__global__ __launch_bounds__(256) void erode_both_kernel(
    const float* __restrict__ xP, const float* __restrict__ xG,
    const float* __restrict__ tmaxP, const float* __restrict__ tmaxG,
    float* __restrict__ yP, float* __restrict__ yG,
    float* ymaxP, float* ymaxG) {
    const float tP_max = *tmaxP, tG_max = *tmaxG;
    const float invP = rcpf(tP_max + 1e-8f);
    const float invG = rcpf(tG_max + 1e-8f);
    for (int idx = blockIdx.x * 256 + threadIdx.x; idx < NPIX;
         idx += gridDim.x * 256) {
        int i = idx & (HW - 1);
        int y = i >> 9;
        int c = i & (W - 1);
        float tP = 0.0f, tG = 0.0f;
        if (y > 0)     { tP += xP[idx - W]; tG += xG[idx - W]; }
        if (y < H - 1) { tP += xP[idx + W]; tG += xG[idx + W]; }
        if (c > 0)     { tP += xP[idx - 1]; tG += xG[idx - 1]; }
        if (c < W - 1) { tP += xP[idx + 1]; tG += xG[idx + 1]; }
        yP[idx] = sig_er(tP * invP);
        yG[idx] = sig_er(tG * invG);
    }
    if (blockIdx.x == 0 && threadIdx.x == 0) {
        *ymaxP = sig_er(tP_max * invP);
        *ymaxG = sig_er(tG_max * invG);
    }
}

// ---------------- dilate both pairs (3x3 sum, clip<=1), squared diff, reduce -
__global__ __launch_bounds__(256) void dil_diff2_kernel(
    const float* __restrict__ cp, float* acc) {
    float s = 0.0f;
    for (int idx = blockIdx.x * 256 + threadIdx.x; idx < NPIX;
         idx += gridDim.x * 256) {
        int i = idx & (HW - 1);
        int y = i >> 9;
        int c = i & (W - 1);
        int bb = idx - i;
        float s0 = 0.0f, s1 = 0.0f, s2 = 0.0f, s3 = 0.0f;
#pragma unroll
        for (int dy = -1; dy <= 1; dy++) {
            int yy = y + dy;
            if ((unsigned)yy < (unsigned)H) {
                int rb = bb + yy * W;
#pragma unroll
                for (int dx = -1; dx <= 1; dx++) {
                    int xx = c + dx;
                    if ((unsigned)xx < (unsigned)W) {
                        int a = rb + xx;
                        s0 += cp[0 * NPIX + a];
                        s1 += cp[1 * NPIX + a];
                        s2 += cp[2 * NPIX + a];
                        s3 += cp[3 * NPIX + a];
                    }
                }
            }
        }
        float d1 = fminf(s0, 1.0f) - fminf(s1, 1.0f);
        float d2 = fminf(s2, 1.0f) - fminf(s3, 1.0f);
        s += d1 * d1 + d2 * d2;
    }
    s = wave_sum(s);
    __shared__ float red[4];
    int tid = threadIdx.x;
    if ((tid & 63) == 0) red[tid >> 6] = s;
    __syncthreads();
    if (tid == 0) atomicAdd(acc, red[0] + red[1] + red[2] + red[3]);
}

__global__ void finalize_kernel(const float* acc, float* out) {
    out[0] = acc[0] * (1.0f / (float)B);
}

// ---------------- launch -----------------------------------------------------
extern "C" void kernel_launch(void* const* d_in, const int* in_sizes, int n_in,
                              void* d_out, int out_size, void* d_ws, size_t ws_size,
                              hipStream_t stream) {
    (void)in_sizes; (void)n_in; (void)out_size; (void)ws_size;
    const float* pred = (const float*)d_in[0];
    const float* gt   = (const float*)d_in[1];
    float* out = (float*)d_out;

    // workspace (floats): S[1024] slots, P1,G1,P2,G2 [N each], CP [4N]
    // slots: 0..2 = P comp-base per level (raw max, ymax1, ymax2)
    //        3..5 = G likewise; 7 = loss acc; 8..11 = t-max; 12,13 scrap
    float* S  = (float*)d_ws;
    float* P1 = S + 1024;
    float* G1 = P1 + NPIX;
    float* P2 = G1 + NPIX;
    float* G2 = P2 + NPIX;
    float* CP = G2 + NPIX;  // 4*NPIX

    hipMemsetAsync(S, 0, 64 * sizeof(float), stream);

    const dim3 b1(256), g1(1024);
    const dim3 b2(16, 16, 1), g2(W / 16, H / 16, B);

    // erosion 1 max pass (also raw maxes of pred/gt for level-0 complement)
    cross_max_both_kernel<<<g1, b1, 0, stream>>>(pred, gt, S + 8, S + 9, S + 0, S + 3);
    erode_both_kernel<<<g1, b1, 0, stream>>>(pred, gt, S + 8, S + 9, P1, G1, S + 1, S + 4);
    // level 0
    cp_quad_kernel<<<g2, b2, 0, stream>>>(pred, gt, S + 0, S + 3, CP);
    dil_diff2_kernel<<<g1, b1, 0, stream>>>(CP, S + 7);
    // erosion 2
    cross_max_both_kernel<<<g1, b1, 0, stream>>>(P1, G1, S + 10, S + 11, S + 12, S + 13);
    erode_both_kernel<<<g1, b1, 0, stream>>>(P1, G1, S + 10, S + 11, P2, G2, S + 2, S + 5);
    // level 1
    cp_quad_kernel<<<g2, b2, 0, stream>>>(P1, G1, S + 1, S + 4, CP);
    dil_diff2_kernel<<<g1, b1, 0, stream>>>(CP, S + 7);
    // level 2
    cp_quad_kernel<<<g2, b2, 0, stream>>>(P2, G2, S + 2, S + 5, CP);
    dil_diff2_kernel<<<g1, b1, 0, stream>>>(CP, S + 7);

    finalize_kernel<<<1, 1, 0, stream>>>(S + 7, out);
}